// Round 6
// baseline (568.553 us; speedup 1.0000x reference)
//
#include <hip/hip_runtime.h>
#include <hip/hip_bf16.h>

#define IN_DIM 128
#define HC 128   // H*C
#define NH 4     // heads
#define CH 32    // channels per head
#define EDGE_DIM 32
#define BSHIFT 6  // 64 dsts per coarse bucket

// ---------------------------------------------------------------------------
// pack two f32 -> bf16x2 (round-to-nearest-even), result uint
// ---------------------------------------------------------------------------
__device__ __forceinline__ unsigned pack_bf16(float a, float b) {
    unsigned ua = __float_as_uint(a), ub = __float_as_uint(b);
    ua += 0x7fffu + ((ua >> 16) & 1u);
    ub += 0x7fffu + ((ub >> 16) & 1u);
    return (ua >> 16) | (ub & 0xffff0000u);
}

// ---------------------------------------------------------------------------
// K0: v_edge[h][k] = sum_c W_edge[k, h*32+c] * att_edge[h, c]   (4x32 floats)
// ---------------------------------------------------------------------------
__global__ void k_vedge(const float* __restrict__ W_edge,
                        const float* __restrict__ att_edge,
                        float* __restrict__ v_edge) {
    int t = threadIdx.x;           // 128 threads
    int h = t >> 5, k = t & 31;
    float s = 0.f;
    #pragma unroll
    for (int c = 0; c < CH; ++c)
        s += W_edge[k * HC + h * CH + c] * att_edge[h * CH + c];
    v_edge[h * EDGE_DIM + k] = s;
}

// ---------------------------------------------------------------------------
// K1: x = point_attr @ W  [N,128] stored as bf16; fused a_src/a_dst epilogue.
// ---------------------------------------------------------------------------
__global__ __launch_bounds__(256) void k_gemm_x(
    const float* __restrict__ A, const float* __restrict__ Wg,
    const float* __restrict__ att_src, const float* __restrict__ att_dst,
    unsigned* __restrict__ xb, float* __restrict__ a_src, float* __restrict__ a_dst,
    int N)
{
    __shared__ float4 Wl[128 * 32];   // 64 KB: W[k][c4]
    __shared__ float4 Rl[128 * 32];   // 64 KB: A rows, k4-index XOR row&31

    int t = threadIdx.x;
    int node0 = blockIdx.x * 128;

    const float4* Wg4 = (const float4*)Wg;
    #pragma unroll
    for (int i = 0; i < 16; ++i) {
        int id = i * 256 + t;
        Wl[id] = Wg4[id];
    }
    const float4* A4 = (const float4*)A;
    #pragma unroll
    for (int i = 0; i < 16; ++i) {
        int id = i * 256 + t;
        int row = id >> 5, c = id & 31;
        float4 v = {0.f, 0.f, 0.f, 0.f};
        if (node0 + row < N) v = A4[(size_t)(node0 + row) * 32 + c];
        Rl[row * 32 + (c ^ (row & 31))] = v;
    }
    __syncthreads();

    int tr = t >> 4, tc = t & 15;
    float4 acc0[8], acc1[8];
    #pragma unroll
    for (int i = 0; i < 8; ++i) {
        acc0[i] = {0.f, 0.f, 0.f, 0.f};
        acc1[i] = {0.f, 0.f, 0.f, 0.f};
    }

    for (int k4 = 0; k4 < 32; ++k4) {
        float4 rv[8];
        #pragma unroll
        for (int i = 0; i < 8; ++i) {
            int r = tr + 16 * i;
            rv[i] = Rl[r * 32 + (k4 ^ (r & 31))];
        }
        #pragma unroll
        for (int kk = 0; kk < 4; ++kk) {
            int k = k4 * 4 + kk;
            float4 w0 = Wl[k * 32 + tc];
            float4 w1 = Wl[k * 32 + 16 + tc];
            #pragma unroll
            for (int i = 0; i < 8; ++i) {
                float a = (kk == 0) ? rv[i].x : (kk == 1) ? rv[i].y
                        : (kk == 2) ? rv[i].z : rv[i].w;
                acc0[i].x += a * w0.x; acc0[i].y += a * w0.y;
                acc0[i].z += a * w0.z; acc0[i].w += a * w0.w;
                acc1[i].x += a * w1.x; acc1[i].y += a * w1.y;
                acc1[i].z += a * w1.z; acc1[i].w += a * w1.w;
            }
        }
    }

    int h0 = tc >> 3;
    int co = (tc & 7) * 4;
    float4 as0 = *(const float4*)&att_src[h0 * CH + co];
    float4 as1 = *(const float4*)&att_src[(h0 + 2) * CH + co];
    float4 ad0 = *(const float4*)&att_dst[h0 * CH + co];
    float4 ad1 = *(const float4*)&att_dst[(h0 + 2) * CH + co];
    uint2* x2 = (uint2*)xb;

    #pragma unroll
    for (int i = 0; i < 8; ++i) {
        int r = tr + 16 * i;
        int node = node0 + r;
        bool ok = node < N;
        if (ok) {
            uint2 p0 = {pack_bf16(acc0[i].x, acc0[i].y), pack_bf16(acc0[i].z, acc0[i].w)};
            uint2 p1 = {pack_bf16(acc1[i].x, acc1[i].y), pack_bf16(acc1[i].z, acc1[i].w)};
            x2[(size_t)node * 32 + tc]      = p0;
            x2[(size_t)node * 32 + 16 + tc] = p1;
        }
        float ps0 = acc0[i].x * as0.x + acc0[i].y * as0.y + acc0[i].z * as0.z + acc0[i].w * as0.w;
        float ps1 = acc1[i].x * as1.x + acc1[i].y * as1.y + acc1[i].z * as1.z + acc1[i].w * as1.w;
        float pd0 = acc0[i].x * ad0.x + acc0[i].y * ad0.y + acc0[i].z * ad0.z + acc0[i].w * ad0.w;
        float pd1 = acc1[i].x * ad1.x + acc1[i].y * ad1.y + acc1[i].z * ad1.z + acc1[i].w * ad1.w;
        #pragma unroll
        for (int m = 1; m <= 4; m <<= 1) {
            ps0 += __shfl_xor(ps0, m); ps1 += __shfl_xor(ps1, m);
            pd0 += __shfl_xor(pd0, m); pd1 += __shfl_xor(pd1, m);
        }
        if (ok && (tc & 7) == 0) {
            a_src[node * 4 + h0]     = ps0;
            a_src[node * 4 + h0 + 2] = ps1;
            a_dst[node * 4 + h0]     = pd0;
            a_dst[node * 4 + h0 + 2] = pd1;
        }
    }
}

// ---------------------------------------------------------------------------
// K2: degree histogram (int atomics only, dst stream)
// ---------------------------------------------------------------------------
__global__ __launch_bounds__(256) void k_degree(const int* __restrict__ ei,
                                                int* __restrict__ degree, int E) {
    int e = blockIdx.x * 256 + threadIdx.x;
    if (e < E) atomicAdd(&degree[ei[E + e]], 1);
}

// ---------------------------------------------------------------------------
// K3a: per-block scan. 1024 thr x 4 elem (int4).
// ---------------------------------------------------------------------------
__global__ __launch_bounds__(1024) void k_scan_blk(
    const int* __restrict__ degree, int* __restrict__ local,
    int* __restrict__ blocksum, int N)
{
    __shared__ int sums[1024];
    int t = threadIdx.x;
    int base = blockIdx.x * 4096 + t * 4;
    int4 d = {0, 0, 0, 0};
    if (base + 3 < N) d = *(const int4*)&degree[base];
    else {
        if (base + 0 < N) d.x = degree[base + 0];
        if (base + 1 < N) d.y = degree[base + 1];
        if (base + 2 < N) d.z = degree[base + 2];
        if (base + 3 < N) d.w = degree[base + 3];
    }
    int s = d.x + d.y + d.z + d.w;
    sums[t] = s;
    __syncthreads();
    #pragma unroll
    for (int dd = 1; dd < 1024; dd <<= 1) {
        int v = (t >= dd) ? sums[t - dd] : 0;
        __syncthreads();
        sums[t] += v;
        __syncthreads();
    }
    int ex = sums[t] - s;
    if (t == 1023) blocksum[blockIdx.x] = sums[1023];
    int4 o;
    o.x = ex;
    o.y = o.x + d.x;
    o.z = o.y + d.y;
    o.w = o.z + d.z;
    if (base + 3 < N) *(int4*)&local[base] = o;
    else {
        if (base + 0 < N) local[base + 0] = o.x;
        if (base + 1 < N) local[base + 1] = o.y;
        if (base + 2 < N) local[base + 2] = o.z;
        if (base + 3 < N) local[base + 3] = o.w;
    }
}

// ---------------------------------------------------------------------------
// K3b: scan block sums in-place -> exclusive block bases; offsets[N] = E.
// ---------------------------------------------------------------------------
__global__ __launch_bounds__(1024) void k_scan_top(
    int* __restrict__ blocksum, int nb, int* __restrict__ offsets, int N)
{
    __shared__ int sums[1024];
    int t = threadIdx.x;
    int v = (t < nb) ? blocksum[t] : 0;
    sums[t] = v;
    __syncthreads();
    #pragma unroll
    for (int d = 1; d < 1024; d <<= 1) {
        int u = (t >= d) ? sums[t - d] : 0;
        __syncthreads();
        sums[t] += u;
        __syncthreads();
    }
    if (t < nb) blocksum[t] = sums[t] - v;
    if (t == nb - 1) offsets[N] = sums[t];
}

// ---------------------------------------------------------------------------
// K3c: add block base; write offsets + cursor.
// ---------------------------------------------------------------------------
__global__ __launch_bounds__(1024) void k_scan_add(
    const int* __restrict__ local, const int* __restrict__ blocksum,
    int* __restrict__ offsets, int* __restrict__ cursor, int N)
{
    int base = blockIdx.x * 4096 + threadIdx.x * 4;
    int bs = blocksum[blockIdx.x];
    if (base + 3 < N) {
        int4 o = *(const int4*)&local[base];
        o.x += bs; o.y += bs; o.z += bs; o.w += bs;
        *(int4*)&offsets[base] = o;
        *(int4*)&cursor[base]  = o;
    } else {
        for (int j = 0; j < 4; ++j)
            if (base + j < N) {
                int o = local[base + j] + bs;
                offsets[base + j] = o;
                cursor[base + j]  = o;
            }
    }
}

// ---------------------------------------------------------------------------
// K3d: coarse bucket cursors: bcur[b] = offsets[b << BSHIFT]
// ---------------------------------------------------------------------------
__global__ __launch_bounds__(256) void k_binit(
    const int* __restrict__ offsets, int* __restrict__ bcur, int NB, int N)
{
    int b = blockIdx.x * 256 + threadIdx.x;
    if (b < NB) {
        int d = b << BSHIFT;
        bcur[b] = offsets[d < N ? d : N];
    }
}

// ---------------------------------------------------------------------------
// K4 (pass 1): edge stream: a_edge dot + APPEND to coarse dst-bucket.
// Payload int4 {src, bf16(ae0,ae1), bf16(ae2,ae3), dst}. Appends to ~1.5K
// hot bucket heads -> time-clustered line fills (vs 100K random slots).
// ---------------------------------------------------------------------------
__global__ __launch_bounds__(256) void k_scatter(
    const float* __restrict__ edge_attr, const int* __restrict__ ei,
    const float* __restrict__ v_edge, int* __restrict__ bcur,
    int4* __restrict__ csr_tmp, int E)
{
    __shared__ float vl[HC];
    int t = threadIdx.x;
    if (t < HC) vl[t] = v_edge[t];
    __syncthreads();

    int e = blockIdx.x * 256 + t;
    if (e >= E) return;

    const float4* ea4 = (const float4*)edge_attr + (size_t)e * 8;
    float ae[4] = {0.f, 0.f, 0.f, 0.f};
    #pragma unroll
    for (int j = 0; j < 8; ++j) {
        float4 v = ea4[j];
        #pragma unroll
        for (int h = 0; h < 4; ++h) {
            const float* vh = &vl[h * 32 + j * 4];
            ae[h] += v.x * vh[0] + v.y * vh[1] + v.z * vh[2] + v.w * vh[3];
        }
    }
    int src = ei[e], dst = ei[E + e];
    int pos = atomicAdd(&bcur[dst >> BSHIFT], 1);
    int4 pk;
    pk.x = src;
    pk.y = (int)pack_bf16(ae[0], ae[1]);
    pk.z = (int)pack_bf16(ae[2], ae[3]);
    pk.w = dst;
    csr_tmp[pos] = pk;
}

// ---------------------------------------------------------------------------
// K4b (pass 2): place records at exact per-dst slots. Reads bucket-ordered
// tmp coalesced; writes land inside the bucket's ~16KB CSR window (L2-hot).
// ---------------------------------------------------------------------------
__global__ __launch_bounds__(256) void k_place(
    const int4* __restrict__ csr_tmp, int* __restrict__ cursor,
    int4* __restrict__ csr, int E)
{
    int e = blockIdx.x * 256 + threadIdx.x;
    if (e >= E) return;
    int4 pk = csr_tmp[e];
    int pos = atomicAdd(&cursor[pk.w], 1);
    csr[pos] = pk;
}

// ---------------------------------------------------------------------------
// K5: fused pull: logit finish (a_src gather + a_dst + exp) + softmax denom +
// weighted sum + bias + LayerNorm + LeakyReLU. 32 lanes/node, lane owns 4
// channels. 4-edge groups with 1-ahead prefetch.
// ---------------------------------------------------------------------------
__global__ __launch_bounds__(256) void k_agg(
    const int* __restrict__ offsets, const int4* __restrict__ csr,
    const float* __restrict__ a_src, const float* __restrict__ a_dst,
    const unsigned* __restrict__ xb, const float* __restrict__ bias,
    const float* __restrict__ gamma, const float* __restrict__ beta,
    float* __restrict__ out, int N)
{
    int t = threadIdx.x;
    int node = blockIdx.x * 8 + (t >> 5);
    int lane = t & 31;
    if (node >= N) return;
    int st = offsets[node], en = offsets[node + 1];
    int hsel = lane >> 3;
    float adst = a_dst[node * 4 + hsel];
    const uint2* x2 = (const uint2*)xb;
    float4 acc = {0.f, 0.f, 0.f, 0.f};
    float denom = 0.f;

    int s_c[4]; float ae_c[4], as_c[4];

    if (st < en) {
        #pragma unroll
        for (int j = 0; j < 4; ++j) {
            bool v = (st + j) < en;
            int a = v ? (st + j) : 0;
            int4 pk = csr[a];
            s_c[j] = pk.x;
            unsigned w = (hsel & 2) ? (unsigned)pk.z : (unsigned)pk.y;
            float e = __uint_as_float((hsel & 1) ? (w & 0xffff0000u) : (w << 16));
            ae_c[j] = v ? e : -1e30f;
        }
        #pragma unroll
        for (int j = 0; j < 4; ++j) as_c[j] = a_src[s_c[j] * 4 + hsel];

        for (int p = st; p < en; p += 4) {
            int pn = p + 4;
            int s_n[4]; float ae_n[4], as_n[4];
            #pragma unroll
            for (int j = 0; j < 4; ++j) {
                bool v = (pn + j) < en;
                int a = v ? (pn + j) : 0;
                int4 pk = csr[a];
                s_n[j] = pk.x;
                unsigned w = (hsel & 2) ? (unsigned)pk.z : (unsigned)pk.y;
                float e = __uint_as_float((hsel & 1) ? (w & 0xffff0000u) : (w << 16));
                ae_n[j] = v ? e : -1e30f;
            }
            #pragma unroll
            for (int j = 0; j < 4; ++j) as_n[j] = a_src[s_n[j] * 4 + hsel];

            #pragma unroll
            for (int j = 0; j < 4; ++j) {
                float al = as_c[j] + adst + ae_c[j];
                al = (al < 0.f) ? 0.2f * al : al;
                float ex = __expf(al);
                denom += ex;
                uint2 xv = x2[(size_t)s_c[j] * 32 + lane];
                float x0 = __uint_as_float(xv.x << 16);
                float x1 = __uint_as_float(xv.x & 0xffff0000u);
                float xA = __uint_as_float(xv.y << 16);
                float x3 = __uint_as_float(xv.y & 0xffff0000u);
                acc.x += ex * x0; acc.y += ex * x1;
                acc.z += ex * xA; acc.w += ex * x3;
            }
            #pragma unroll
            for (int j = 0; j < 4; ++j) {
                s_c[j] = s_n[j]; ae_c[j] = ae_n[j]; as_c[j] = as_n[j];
            }
        }
    }
    float inv = 1.f / (denom + 1e-16f);
    float4 o = {acc.x * inv, acc.y * inv, acc.z * inv, acc.w * inv};

    // fused +bias, LayerNorm(128), LeakyReLU(0.01); reduce across 32 lanes
    int c = lane * 4;
    float4 b4 = *(const float4*)&bias[c];
    o.x += b4.x; o.y += b4.y; o.z += b4.z; o.w += b4.w;
    float s = o.x + o.y + o.z + o.w;
    #pragma unroll
    for (int m = 1; m < 32; m <<= 1) s += __shfl_xor(s, m, 32);
    float mu = s * (1.0f / 128.0f);
    float d0 = o.x - mu, d1 = o.y - mu, d2 = o.z - mu, d3 = o.w - mu;
    float q = d0 * d0 + d1 * d1 + d2 * d2 + d3 * d3;
    #pragma unroll
    for (int m = 1; m < 32; m <<= 1) q += __shfl_xor(q, m, 32);
    float rstd = rsqrtf(q * (1.0f / 128.0f) + 1e-5f);
    float4 g4 = *(const float4*)&gamma[c];
    float4 be4 = *(const float4*)&beta[c];
    float y0 = d0 * rstd * g4.x + be4.x;
    float y1 = d1 * rstd * g4.y + be4.y;
    float y2 = d2 * rstd * g4.z + be4.z;
    float y3 = d3 * rstd * g4.w + be4.w;
    y0 = (y0 < 0.f) ? 0.01f * y0 : y0;
    y1 = (y1 < 0.f) ? 0.01f * y1 : y1;
    y2 = (y2 < 0.f) ? 0.01f * y2 : y2;
    y3 = (y3 < 0.f) ? 0.01f * y3 : y3;
    float4 r = {y0, y1, y2, y3};
    ((float4*)out)[(size_t)node * 32 + lane] = r;
}

// ---------------------------------------------------------------------------
extern "C" void kernel_launch(void* const* d_in, const int* in_sizes, int n_in,
                              void* d_out, int out_size, void* d_ws, size_t ws_size,
                              hipStream_t stream) {
    const float* point_attr = (const float*)d_in[0];
    const int*   edge_index = (const int*)d_in[1];
    const float* edge_attr  = (const float*)d_in[2];
    const float* W          = (const float*)d_in[3];
    const float* att_src    = (const float*)d_in[4];
    const float* att_dst    = (const float*)d_in[5];
    const float* W_edge     = (const float*)d_in[6];
    const float* att_edge   = (const float*)d_in[7];
    const float* bias       = (const float*)d_in[8];
    const float* ln_gamma   = (const float*)d_in[9];
    const float* ln_beta    = (const float*)d_in[10];

    int N = in_sizes[0] / IN_DIM;
    int E = in_sizes[2] / EDGE_DIM;
    float* out = (float*)d_out;

    char* ws = (char*)d_ws;
    size_t off = 0;
    auto alloc = [&](size_t bytes) {
        void* p = ws + off;
        off += (bytes + 255) & ~(size_t)255;
        return p;
    };
    unsigned* xb     = (unsigned*)alloc((size_t)N * 128 * 2);   // bf16 x
    float* a_src     = (float*)alloc((size_t)N * 4 * 4);
    float* a_dst     = (float*)alloc((size_t)N * 4 * 4);
    int*   degree    = (int*)alloc((size_t)N * 4);
    int*   offsets   = (int*)alloc((size_t)(N + 1) * 4);
    int*   cursor    = (int*)alloc((size_t)N * 4);
    int*   scanloc   = (int*)alloc((size_t)N * 4);
    int*   blocksum  = (int*)alloc(1024 * 4);
    float* v_edge    = (float*)alloc(128 * 4);
    int*   bcur      = (int*)alloc((size_t)((N >> BSHIFT) + 2) * 4);
    int4*  csr       = (int4*)alloc((size_t)E * 16);
    int4*  csr_tmp   = (int4*)alloc((size_t)E * 16);

    hipMemsetAsync(degree, 0, (size_t)N * 4, stream);

    int nb = (N + 4095) / 4096;
    int NB = (N + (1 << BSHIFT) - 1) >> BSHIFT;

    k_vedge<<<1, 128, 0, stream>>>(W_edge, att_edge, v_edge);
    k_gemm_x<<<(N + 127) / 128, 256, 0, stream>>>(point_attr, W, att_src, att_dst,
                                                  xb, a_src, a_dst, N);
    k_degree<<<(E + 255) / 256, 256, 0, stream>>>(edge_index, degree, E);
    k_scan_blk<<<nb, 1024, 0, stream>>>(degree, scanloc, blocksum, N);
    k_scan_top<<<1, 1024, 0, stream>>>(blocksum, nb, offsets, N);
    k_scan_add<<<nb, 1024, 0, stream>>>(scanloc, blocksum, offsets, cursor, N);
    k_binit<<<(NB + 255) / 256, 256, 0, stream>>>(offsets, bcur, NB, N);
    k_scatter<<<(E + 255) / 256, 256, 0, stream>>>(edge_attr, edge_index, v_edge,
                                                   bcur, csr_tmp, E);
    k_place<<<(E + 255) / 256, 256, 0, stream>>>(csr_tmp, cursor, csr, E);
    k_agg<<<(N + 7) / 8, 256, 0, stream>>>(offsets, csr, a_src, a_dst, xb,
                                           bias, ln_gamma, ln_beta, out, N);
}

// Round 7
// 415.722 us; speedup vs baseline: 1.3676x; 1.3676x over previous
//
#include <hip/hip_runtime.h>
#include <hip/hip_bf16.h>

#define IN_DIM 128
#define HC 128   // H*C
#define NH 4     // heads
#define CH 32    // channels per head
#define EDGE_DIM 32

// ---------------------------------------------------------------------------
// pack two f32 -> bf16x2 (round-to-nearest-even), result uint
// ---------------------------------------------------------------------------
__device__ __forceinline__ unsigned pack_bf16(float a, float b) {
    unsigned ua = __float_as_uint(a), ub = __float_as_uint(b);
    ua += 0x7fffu + ((ua >> 16) & 1u);
    ub += 0x7fffu + ((ub >> 16) & 1u);
    return (ua >> 16) | (ub & 0xffff0000u);
}

// ---------------------------------------------------------------------------
// K0: v_edge[h][k] = sum_c W_edge[k, h*32+c] * att_edge[h, c]   (4x32 floats)
// ---------------------------------------------------------------------------
__global__ void k_vedge(const float* __restrict__ W_edge,
                        const float* __restrict__ att_edge,
                        float* __restrict__ v_edge) {
    int t = threadIdx.x;           // 128 threads
    int h = t >> 5, k = t & 31;
    float s = 0.f;
    #pragma unroll
    for (int c = 0; c < CH; ++c)
        s += W_edge[k * HC + h * CH + c] * att_edge[h * CH + c];
    v_edge[h * EDGE_DIM + k] = s;
}

// ---------------------------------------------------------------------------
// K1: x = point_attr @ W  [N,128] stored as bf16; fused a_src/a_dst epilogue.
// ---------------------------------------------------------------------------
__global__ __launch_bounds__(256) void k_gemm_x(
    const float* __restrict__ A, const float* __restrict__ Wg,
    const float* __restrict__ att_src, const float* __restrict__ att_dst,
    unsigned* __restrict__ xb, float* __restrict__ a_src, float* __restrict__ a_dst,
    int N)
{
    __shared__ float4 Wl[128 * 32];   // 64 KB: W[k][c4]
    __shared__ float4 Rl[128 * 32];   // 64 KB: A rows, k4-index XOR row&31

    int t = threadIdx.x;
    int node0 = blockIdx.x * 128;

    const float4* Wg4 = (const float4*)Wg;
    #pragma unroll
    for (int i = 0; i < 16; ++i) {
        int id = i * 256 + t;
        Wl[id] = Wg4[id];
    }
    const float4* A4 = (const float4*)A;
    #pragma unroll
    for (int i = 0; i < 16; ++i) {
        int id = i * 256 + t;
        int row = id >> 5, c = id & 31;
        float4 v = {0.f, 0.f, 0.f, 0.f};
        if (node0 + row < N) v = A4[(size_t)(node0 + row) * 32 + c];
        Rl[row * 32 + (c ^ (row & 31))] = v;
    }
    __syncthreads();

    int tr = t >> 4, tc = t & 15;
    float4 acc0[8], acc1[8];
    #pragma unroll
    for (int i = 0; i < 8; ++i) {
        acc0[i] = {0.f, 0.f, 0.f, 0.f};
        acc1[i] = {0.f, 0.f, 0.f, 0.f};
    }

    for (int k4 = 0; k4 < 32; ++k4) {
        float4 rv[8];
        #pragma unroll
        for (int i = 0; i < 8; ++i) {
            int r = tr + 16 * i;
            rv[i] = Rl[r * 32 + (k4 ^ (r & 31))];
        }
        #pragma unroll
        for (int kk = 0; kk < 4; ++kk) {
            int k = k4 * 4 + kk;
            float4 w0 = Wl[k * 32 + tc];
            float4 w1 = Wl[k * 32 + 16 + tc];
            #pragma unroll
            for (int i = 0; i < 8; ++i) {
                float a = (kk == 0) ? rv[i].x : (kk == 1) ? rv[i].y
                        : (kk == 2) ? rv[i].z : rv[i].w;
                acc0[i].x += a * w0.x; acc0[i].y += a * w0.y;
                acc0[i].z += a * w0.z; acc0[i].w += a * w0.w;
                acc1[i].x += a * w1.x; acc1[i].y += a * w1.y;
                acc1[i].z += a * w1.z; acc1[i].w += a * w1.w;
            }
        }
    }

    int h0 = tc >> 3;
    int co = (tc & 7) * 4;
    float4 as0 = *(const float4*)&att_src[h0 * CH + co];
    float4 as1 = *(const float4*)&att_src[(h0 + 2) * CH + co];
    float4 ad0 = *(const float4*)&att_dst[h0 * CH + co];
    float4 ad1 = *(const float4*)&att_dst[(h0 + 2) * CH + co];
    uint2* x2 = (uint2*)xb;

    #pragma unroll
    for (int i = 0; i < 8; ++i) {
        int r = tr + 16 * i;
        int node = node0 + r;
        bool ok = node < N;
        if (ok) {
            uint2 p0 = {pack_bf16(acc0[i].x, acc0[i].y), pack_bf16(acc0[i].z, acc0[i].w)};
            uint2 p1 = {pack_bf16(acc1[i].x, acc1[i].y), pack_bf16(acc1[i].z, acc1[i].w)};
            x2[(size_t)node * 32 + tc]      = p0;
            x2[(size_t)node * 32 + 16 + tc] = p1;
        }
        float ps0 = acc0[i].x * as0.x + acc0[i].y * as0.y + acc0[i].z * as0.z + acc0[i].w * as0.w;
        float ps1 = acc1[i].x * as1.x + acc1[i].y * as1.y + acc1[i].z * as1.z + acc1[i].w * as1.w;
        float pd0 = acc0[i].x * ad0.x + acc0[i].y * ad0.y + acc0[i].z * ad0.z + acc0[i].w * ad0.w;
        float pd1 = acc1[i].x * ad1.x + acc1[i].y * ad1.y + acc1[i].z * ad1.z + acc1[i].w * ad1.w;
        #pragma unroll
        for (int m = 1; m <= 4; m <<= 1) {
            ps0 += __shfl_xor(ps0, m); ps1 += __shfl_xor(ps1, m);
            pd0 += __shfl_xor(pd0, m); pd1 += __shfl_xor(pd1, m);
        }
        if (ok && (tc & 7) == 0) {
            a_src[node * 4 + h0]     = ps0;
            a_src[node * 4 + h0 + 2] = ps1;
            a_dst[node * 4 + h0]     = pd0;
            a_dst[node * 4 + h0 + 2] = pd1;
        }
    }
}

// ---------------------------------------------------------------------------
// K2: degree histogram (int atomics only, dst stream)
// ---------------------------------------------------------------------------
__global__ __launch_bounds__(256) void k_degree(const int* __restrict__ ei,
                                                int* __restrict__ degree, int E) {
    int e = blockIdx.x * 256 + threadIdx.x;
    if (e < E) atomicAdd(&degree[ei[E + e]], 1);
}

// ---------------------------------------------------------------------------
// K3a: per-block scan. 1024 thr x 4 elem (int4).
// ---------------------------------------------------------------------------
__global__ __launch_bounds__(1024) void k_scan_blk(
    const int* __restrict__ degree, int* __restrict__ local,
    int* __restrict__ blocksum, int N)
{
    __shared__ int sums[1024];
    int t = threadIdx.x;
    int base = blockIdx.x * 4096 + t * 4;
    int4 d = {0, 0, 0, 0};
    if (base + 3 < N) d = *(const int4*)&degree[base];
    else {
        if (base + 0 < N) d.x = degree[base + 0];
        if (base + 1 < N) d.y = degree[base + 1];
        if (base + 2 < N) d.z = degree[base + 2];
        if (base + 3 < N) d.w = degree[base + 3];
    }
    int s = d.x + d.y + d.z + d.w;
    sums[t] = s;
    __syncthreads();
    #pragma unroll
    for (int dd = 1; dd < 1024; dd <<= 1) {
        int v = (t >= dd) ? sums[t - dd] : 0;
        __syncthreads();
        sums[t] += v;
        __syncthreads();
    }
    int ex = sums[t] - s;
    if (t == 1023) blocksum[blockIdx.x] = sums[1023];
    int4 o;
    o.x = ex;
    o.y = o.x + d.x;
    o.z = o.y + d.y;
    o.w = o.z + d.z;
    if (base + 3 < N) *(int4*)&local[base] = o;
    else {
        if (base + 0 < N) local[base + 0] = o.x;
        if (base + 1 < N) local[base + 1] = o.y;
        if (base + 2 < N) local[base + 2] = o.z;
        if (base + 3 < N) local[base + 3] = o.w;
    }
}

// ---------------------------------------------------------------------------
// K3b: scan block sums in-place -> exclusive block bases; offsets[N] = E.
// ---------------------------------------------------------------------------
__global__ __launch_bounds__(1024) void k_scan_top(
    int* __restrict__ blocksum, int nb, int* __restrict__ offsets, int N)
{
    __shared__ int sums[1024];
    int t = threadIdx.x;
    int v = (t < nb) ? blocksum[t] : 0;
    sums[t] = v;
    __syncthreads();
    #pragma unroll
    for (int d = 1; d < 1024; d <<= 1) {
        int u = (t >= d) ? sums[t - d] : 0;
        __syncthreads();
        sums[t] += u;
        __syncthreads();
    }
    if (t < nb) blocksum[t] = sums[t] - v;
    if (t == nb - 1) offsets[N] = sums[t];
}

// ---------------------------------------------------------------------------
// K3c: add block base; write offsets + cursor.
// ---------------------------------------------------------------------------
__global__ __launch_bounds__(1024) void k_scan_add(
    const int* __restrict__ local, const int* __restrict__ blocksum,
    int* __restrict__ offsets, int* __restrict__ cursor, int N)
{
    int base = blockIdx.x * 4096 + threadIdx.x * 4;
    int bs = blocksum[blockIdx.x];
    if (base + 3 < N) {
        int4 o = *(const int4*)&local[base];
        o.x += bs; o.y += bs; o.z += bs; o.w += bs;
        *(int4*)&offsets[base] = o;
        *(int4*)&cursor[base]  = o;
    } else {
        for (int j = 0; j < 4; ++j)
            if (base + j < N) {
                int o = local[base + j] + bs;
                offsets[base + j] = o;
                cursor[base + j]  = o;
            }
    }
}

// ---------------------------------------------------------------------------
// K4: edge stream: a_edge dot. Payload written COALESCED at edge index e
// (16B stream, no amplification); only a 4B perm entry is scattered
// (6.4MB array, L2-resident -> low write amplification).
// ---------------------------------------------------------------------------
__global__ __launch_bounds__(256) void k_scatter(
    const float* __restrict__ edge_attr, const int* __restrict__ ei,
    const float* __restrict__ v_edge, int* __restrict__ cursor,
    int4* __restrict__ payload, int* __restrict__ perm, int E)
{
    __shared__ float vl[HC];
    int t = threadIdx.x;
    if (t < HC) vl[t] = v_edge[t];
    __syncthreads();

    int e = blockIdx.x * 256 + t;
    if (e >= E) return;

    const float4* ea4 = (const float4*)edge_attr + (size_t)e * 8;
    float ae[4] = {0.f, 0.f, 0.f, 0.f};
    #pragma unroll
    for (int j = 0; j < 8; ++j) {
        float4 v = ea4[j];
        #pragma unroll
        for (int h = 0; h < 4; ++h) {
            const float* vh = &vl[h * 32 + j * 4];
            ae[h] += v.x * vh[0] + v.y * vh[1] + v.z * vh[2] + v.w * vh[3];
        }
    }
    int src = ei[e], dst = ei[E + e];
    int4 pk;
    pk.x = src;
    pk.y = (int)pack_bf16(ae[0], ae[1]);
    pk.z = (int)pack_bf16(ae[2], ae[3]);
    pk.w = 0;
    payload[e] = pk;                       // coalesced
    int pos = atomicAdd(&cursor[dst], 1);  // 100K addrs: low contention
    perm[pos] = e;                         // scattered 4B
}

// ---------------------------------------------------------------------------
// K5: fused pull: e=perm[p] (seq) -> payload[e] (L3 gather) -> a_src gather,
// exp, softmax denom + weighted sum + bias + LayerNorm + LeakyReLU.
// 32 lanes/node, lane owns 4 channels. 4-edge groups, 1-ahead prefetch.
// ---------------------------------------------------------------------------
__global__ __launch_bounds__(256) void k_agg(
    const int* __restrict__ offsets, const int* __restrict__ perm,
    const int4* __restrict__ payload,
    const float* __restrict__ a_src, const float* __restrict__ a_dst,
    const unsigned* __restrict__ xb, const float* __restrict__ bias,
    const float* __restrict__ gamma, const float* __restrict__ beta,
    float* __restrict__ out, int N)
{
    int t = threadIdx.x;
    int node = blockIdx.x * 8 + (t >> 5);
    int lane = t & 31;
    if (node >= N) return;
    int st = offsets[node], en = offsets[node + 1];
    int hsel = lane >> 3;
    float adst = a_dst[node * 4 + hsel];
    const uint2* x2 = (const uint2*)xb;
    float4 acc = {0.f, 0.f, 0.f, 0.f};
    float denom = 0.f;

    int s_c[4]; float ae_c[4], as_c[4];

    if (st < en) {
        #pragma unroll
        for (int j = 0; j < 4; ++j) {
            bool v = (st + j) < en;
            int a = v ? (st + j) : st;
            int4 pk = payload[perm[a]];
            s_c[j] = pk.x;
            unsigned w = (hsel & 2) ? (unsigned)pk.z : (unsigned)pk.y;
            float e = __uint_as_float((hsel & 1) ? (w & 0xffff0000u) : (w << 16));
            ae_c[j] = v ? e : -1e30f;
        }
        #pragma unroll
        for (int j = 0; j < 4; ++j) as_c[j] = a_src[s_c[j] * 4 + hsel];

        for (int p = st; p < en; p += 4) {
            int pn = p + 4;
            int s_n[4]; float ae_n[4], as_n[4];
            #pragma unroll
            for (int j = 0; j < 4; ++j) {
                bool v = (pn + j) < en;
                int a = v ? (pn + j) : st;
                int4 pk = payload[perm[a]];
                s_n[j] = pk.x;
                unsigned w = (hsel & 2) ? (unsigned)pk.z : (unsigned)pk.y;
                float e = __uint_as_float((hsel & 1) ? (w & 0xffff0000u) : (w << 16));
                ae_n[j] = v ? e : -1e30f;
            }
            #pragma unroll
            for (int j = 0; j < 4; ++j) as_n[j] = a_src[s_n[j] * 4 + hsel];

            #pragma unroll
            for (int j = 0; j < 4; ++j) {
                float al = as_c[j] + adst + ae_c[j];
                al = (al < 0.f) ? 0.2f * al : al;
                float ex = __expf(al);
                denom += ex;
                uint2 xv = x2[(size_t)s_c[j] * 32 + lane];
                float x0 = __uint_as_float(xv.x << 16);
                float x1 = __uint_as_float(xv.x & 0xffff0000u);
                float xA = __uint_as_float(xv.y << 16);
                float x3 = __uint_as_float(xv.y & 0xffff0000u);
                acc.x += ex * x0; acc.y += ex * x1;
                acc.z += ex * xA; acc.w += ex * x3;
            }
            #pragma unroll
            for (int j = 0; j < 4; ++j) {
                s_c[j] = s_n[j]; ae_c[j] = ae_n[j]; as_c[j] = as_n[j];
            }
        }
    }
    float inv = 1.f / (denom + 1e-16f);
    float4 o = {acc.x * inv, acc.y * inv, acc.z * inv, acc.w * inv};

    // fused +bias, LayerNorm(128), LeakyReLU(0.01); reduce across 32 lanes
    int c = lane * 4;
    float4 b4 = *(const float4*)&bias[c];
    o.x += b4.x; o.y += b4.y; o.z += b4.z; o.w += b4.w;
    float s = o.x + o.y + o.z + o.w;
    #pragma unroll
    for (int m = 1; m < 32; m <<= 1) s += __shfl_xor(s, m, 32);
    float mu = s * (1.0f / 128.0f);
    float d0 = o.x - mu, d1 = o.y - mu, d2 = o.z - mu, d3 = o.w - mu;
    float q = d0 * d0 + d1 * d1 + d2 * d2 + d3 * d3;
    #pragma unroll
    for (int m = 1; m < 32; m <<= 1) q += __shfl_xor(q, m, 32);
    float rstd = rsqrtf(q * (1.0f / 128.0f) + 1e-5f);
    float4 g4 = *(const float4*)&gamma[c];
    float4 be4 = *(const float4*)&beta[c];
    float y0 = d0 * rstd * g4.x + be4.x;
    float y1 = d1 * rstd * g4.y + be4.y;
    float y2 = d2 * rstd * g4.z + be4.z;
    float y3 = d3 * rstd * g4.w + be4.w;
    y0 = (y0 < 0.f) ? 0.01f * y0 : y0;
    y1 = (y1 < 0.f) ? 0.01f * y1 : y1;
    y2 = (y2 < 0.f) ? 0.01f * y2 : y2;
    y3 = (y3 < 0.f) ? 0.01f * y3 : y3;
    float4 r = {y0, y1, y2, y3};
    ((float4*)out)[(size_t)node * 32 + lane] = r;
}

// ---------------------------------------------------------------------------
extern "C" void kernel_launch(void* const* d_in, const int* in_sizes, int n_in,
                              void* d_out, int out_size, void* d_ws, size_t ws_size,
                              hipStream_t stream) {
    const float* point_attr = (const float*)d_in[0];
    const int*   edge_index = (const int*)d_in[1];
    const float* edge_attr  = (const float*)d_in[2];
    const float* W          = (const float*)d_in[3];
    const float* att_src    = (const float*)d_in[4];
    const float* att_dst    = (const float*)d_in[5];
    const float* W_edge     = (const float*)d_in[6];
    const float* att_edge   = (const float*)d_in[7];
    const float* bias       = (const float*)d_in[8];
    const float* ln_gamma   = (const float*)d_in[9];
    const float* ln_beta    = (const float*)d_in[10];

    int N = in_sizes[0] / IN_DIM;
    int E = in_sizes[2] / EDGE_DIM;
    float* out = (float*)d_out;

    char* ws = (char*)d_ws;
    size_t off = 0;
    auto alloc = [&](size_t bytes) {
        void* p = ws + off;
        off += (bytes + 255) & ~(size_t)255;
        return p;
    };
    unsigned* xb     = (unsigned*)alloc((size_t)N * 128 * 2);   // bf16 x
    float* a_src     = (float*)alloc((size_t)N * 4 * 4);
    float* a_dst     = (float*)alloc((size_t)N * 4 * 4);
    int*   degree    = (int*)alloc((size_t)N * 4);
    int*   offsets   = (int*)alloc((size_t)(N + 1) * 4);
    int*   cursor    = (int*)alloc((size_t)N * 4);
    int*   scanloc   = (int*)alloc((size_t)N * 4);
    int*   blocksum  = (int*)alloc(1024 * 4);
    float* v_edge    = (float*)alloc(128 * 4);
    int4*  payload   = (int4*)alloc((size_t)E * 16);
    int*   perm      = (int*)alloc((size_t)E * 4);

    hipMemsetAsync(degree, 0, (size_t)N * 4, stream);

    int nb = (N + 4095) / 4096;

    k_vedge<<<1, 128, 0, stream>>>(W_edge, att_edge, v_edge);
    k_gemm_x<<<(N + 127) / 128, 256, 0, stream>>>(point_attr, W, att_src, att_dst,
                                                  xb, a_src, a_dst, N);
    k_degree<<<(E + 255) / 256, 256, 0, stream>>>(edge_index, degree, E);
    k_scan_blk<<<nb, 1024, 0, stream>>>(degree, scanloc, blocksum, N);
    k_scan_top<<<1, 1024, 0, stream>>>(blocksum, nb, offsets, N);
    k_scan_add<<<nb, 1024, 0, stream>>>(scanloc, blocksum, offsets, cursor, N);
    k_scatter<<<(E + 255) / 256, 256, 0, stream>>>(edge_attr, edge_index, v_edge,
                                                   cursor, payload, perm, E);
    k_agg<<<(N + 7) / 8, 256, 0, stream>>>(offsets, perm, payload, a_src, a_dst,
                                           xb, bias, ln_gamma, ln_beta, out, N);
}

// Round 9
// 388.697 us; speedup vs baseline: 1.4627x; 1.0695x over previous
//
#include <hip/hip_runtime.h>
#include <hip/hip_bf16.h>

#define IN_DIM 128
#define HC 128   // H*C
#define NH 4     // heads
#define CH 32    // channels per head
#define EDGE_DIM 32

typedef int   i4_t __attribute__((ext_vector_type(4)));
typedef float f4_t __attribute__((ext_vector_type(4)));

__device__ __forceinline__ void nt_store_i4(int4* p, int4 v) {
    i4_t pk = {v.x, v.y, v.z, v.w};
    __builtin_nontemporal_store(pk, (i4_t*)p);
}
__device__ __forceinline__ void nt_store_f4(float4* p, float4 v) {
    f4_t pk = {v.x, v.y, v.z, v.w};
    __builtin_nontemporal_store(pk, (f4_t*)p);
}

// ---------------------------------------------------------------------------
// pack two f32 -> bf16x2 (round-to-nearest-even), result uint
// ---------------------------------------------------------------------------
__device__ __forceinline__ unsigned pack_bf16(float a, float b) {
    unsigned ua = __float_as_uint(a), ub = __float_as_uint(b);
    ua += 0x7fffu + ((ua >> 16) & 1u);
    ub += 0x7fffu + ((ub >> 16) & 1u);
    return (ua >> 16) | (ub & 0xffff0000u);
}

// ---------------------------------------------------------------------------
// K0: v_edge[h][k] = sum_c W_edge[k, h*32+c] * att_edge[h, c]   (4x32 floats)
// ---------------------------------------------------------------------------
__global__ void k_vedge(const float* __restrict__ W_edge,
                        const float* __restrict__ att_edge,
                        float* __restrict__ v_edge) {
    int t = threadIdx.x;           // 128 threads
    int h = t >> 5, k = t & 31;
    float s = 0.f;
    #pragma unroll
    for (int c = 0; c < CH; ++c)
        s += W_edge[k * HC + h * CH + c] * att_edge[h * CH + c];
    v_edge[h * EDGE_DIM + k] = s;
}

// ---------------------------------------------------------------------------
// K1: x = point_attr @ W  [N,128] stored as bf16; fused a_src/a_dst epilogue.
// ---------------------------------------------------------------------------
__global__ __launch_bounds__(256) void k_gemm_x(
    const float* __restrict__ A, const float* __restrict__ Wg,
    const float* __restrict__ att_src, const float* __restrict__ att_dst,
    unsigned* __restrict__ xb, float* __restrict__ a_src, float* __restrict__ a_dst,
    int N)
{
    __shared__ float4 Wl[128 * 32];   // 64 KB: W[k][c4]
    __shared__ float4 Rl[128 * 32];   // 64 KB: A rows, k4-index XOR row&31

    int t = threadIdx.x;
    int node0 = blockIdx.x * 128;

    const float4* Wg4 = (const float4*)Wg;
    #pragma unroll
    for (int i = 0; i < 16; ++i) {
        int id = i * 256 + t;
        Wl[id] = Wg4[id];
    }
    const float4* A4 = (const float4*)A;
    #pragma unroll
    for (int i = 0; i < 16; ++i) {
        int id = i * 256 + t;
        int row = id >> 5, c = id & 31;
        float4 v = {0.f, 0.f, 0.f, 0.f};
        if (node0 + row < N) v = A4[(size_t)(node0 + row) * 32 + c];
        Rl[row * 32 + (c ^ (row & 31))] = v;
    }
    __syncthreads();

    int tr = t >> 4, tc = t & 15;
    float4 acc0[8], acc1[8];
    #pragma unroll
    for (int i = 0; i < 8; ++i) {
        acc0[i] = {0.f, 0.f, 0.f, 0.f};
        acc1[i] = {0.f, 0.f, 0.f, 0.f};
    }

    for (int k4 = 0; k4 < 32; ++k4) {
        float4 rv[8];
        #pragma unroll
        for (int i = 0; i < 8; ++i) {
            int r = tr + 16 * i;
            rv[i] = Rl[r * 32 + (k4 ^ (r & 31))];
        }
        #pragma unroll
        for (int kk = 0; kk < 4; ++kk) {
            int k = k4 * 4 + kk;
            float4 w0 = Wl[k * 32 + tc];
            float4 w1 = Wl[k * 32 + 16 + tc];
            #pragma unroll
            for (int i = 0; i < 8; ++i) {
                float a = (kk == 0) ? rv[i].x : (kk == 1) ? rv[i].y
                        : (kk == 2) ? rv[i].z : rv[i].w;
                acc0[i].x += a * w0.x; acc0[i].y += a * w0.y;
                acc0[i].z += a * w0.z; acc0[i].w += a * w0.w;
                acc1[i].x += a * w1.x; acc1[i].y += a * w1.y;
                acc1[i].z += a * w1.z; acc1[i].w += a * w1.w;
            }
        }
    }

    int h0 = tc >> 3;
    int co = (tc & 7) * 4;
    float4 as0 = *(const float4*)&att_src[h0 * CH + co];
    float4 as1 = *(const float4*)&att_src[(h0 + 2) * CH + co];
    float4 ad0 = *(const float4*)&att_dst[h0 * CH + co];
    float4 ad1 = *(const float4*)&att_dst[(h0 + 2) * CH + co];
    uint2* x2 = (uint2*)xb;

    #pragma unroll
    for (int i = 0; i < 8; ++i) {
        int r = tr + 16 * i;
        int node = node0 + r;
        bool ok = node < N;
        if (ok) {
            uint2 p0 = {pack_bf16(acc0[i].x, acc0[i].y), pack_bf16(acc0[i].z, acc0[i].w)};
            uint2 p1 = {pack_bf16(acc1[i].x, acc1[i].y), pack_bf16(acc1[i].z, acc1[i].w)};
            x2[(size_t)node * 32 + tc]      = p0;
            x2[(size_t)node * 32 + 16 + tc] = p1;
        }
        float ps0 = acc0[i].x * as0.x + acc0[i].y * as0.y + acc0[i].z * as0.z + acc0[i].w * as0.w;
        float ps1 = acc1[i].x * as1.x + acc1[i].y * as1.y + acc1[i].z * as1.z + acc1[i].w * as1.w;
        float pd0 = acc0[i].x * ad0.x + acc0[i].y * ad0.y + acc0[i].z * ad0.z + acc0[i].w * ad0.w;
        float pd1 = acc1[i].x * ad1.x + acc1[i].y * ad1.y + acc1[i].z * ad1.z + acc1[i].w * ad1.w;
        #pragma unroll
        for (int m = 1; m <= 4; m <<= 1) {
            ps0 += __shfl_xor(ps0, m); ps1 += __shfl_xor(ps1, m);
            pd0 += __shfl_xor(pd0, m); pd1 += __shfl_xor(pd1, m);
        }
        if (ok && (tc & 7) == 0) {
            a_src[node * 4 + h0]     = ps0;
            a_src[node * 4 + h0 + 2] = ps1;
            a_dst[node * 4 + h0]     = pd0;
            a_dst[node * 4 + h0 + 2] = pd1;
        }
    }
}

// ---------------------------------------------------------------------------
// K2: degree histogram (int atomics only, dst stream)
// ---------------------------------------------------------------------------
__global__ __launch_bounds__(256) void k_degree(const int* __restrict__ ei,
                                                int* __restrict__ degree, int E) {
    int e = blockIdx.x * 256 + threadIdx.x;
    if (e < E) atomicAdd(&degree[ei[E + e]], 1);
}

// ---------------------------------------------------------------------------
// K3a: per-block scan. 1024 thr x 4 elem (int4).
// ---------------------------------------------------------------------------
__global__ __launch_bounds__(1024) void k_scan_blk(
    const int* __restrict__ degree, int* __restrict__ local,
    int* __restrict__ blocksum, int N)
{
    __shared__ int sums[1024];
    int t = threadIdx.x;
    int base = blockIdx.x * 4096 + t * 4;
    int4 d = {0, 0, 0, 0};
    if (base + 3 < N) d = *(const int4*)&degree[base];
    else {
        if (base + 0 < N) d.x = degree[base + 0];
        if (base + 1 < N) d.y = degree[base + 1];
        if (base + 2 < N) d.z = degree[base + 2];
        if (base + 3 < N) d.w = degree[base + 3];
    }
    int s = d.x + d.y + d.z + d.w;
    sums[t] = s;
    __syncthreads();
    #pragma unroll
    for (int dd = 1; dd < 1024; dd <<= 1) {
        int v = (t >= dd) ? sums[t - dd] : 0;
        __syncthreads();
        sums[t] += v;
        __syncthreads();
    }
    int ex = sums[t] - s;
    if (t == 1023) blocksum[blockIdx.x] = sums[1023];
    int4 o;
    o.x = ex;
    o.y = o.x + d.x;
    o.z = o.y + d.y;
    o.w = o.z + d.z;
    if (base + 3 < N) *(int4*)&local[base] = o;
    else {
        if (base + 0 < N) local[base + 0] = o.x;
        if (base + 1 < N) local[base + 1] = o.y;
        if (base + 2 < N) local[base + 2] = o.z;
        if (base + 3 < N) local[base + 3] = o.w;
    }
}

// ---------------------------------------------------------------------------
// K3b: scan block sums in-place -> exclusive block bases; offsets[N] = E.
// ---------------------------------------------------------------------------
__global__ __launch_bounds__(1024) void k_scan_top(
    int* __restrict__ blocksum, int nb, int* __restrict__ offsets, int N)
{
    __shared__ int sums[1024];
    int t = threadIdx.x;
    int v = (t < nb) ? blocksum[t] : 0;
    sums[t] = v;
    __syncthreads();
    #pragma unroll
    for (int d = 1; d < 1024; d <<= 1) {
        int u = (t >= d) ? sums[t - d] : 0;
        __syncthreads();
        sums[t] += u;
        __syncthreads();
    }
    if (t < nb) blocksum[t] = sums[t] - v;
    if (t == nb - 1) offsets[N] = sums[t];
}

// ---------------------------------------------------------------------------
// K3c: add block base; write offsets + cursor.
// ---------------------------------------------------------------------------
__global__ __launch_bounds__(1024) void k_scan_add(
    const int* __restrict__ local, const int* __restrict__ blocksum,
    int* __restrict__ offsets, int* __restrict__ cursor, int N)
{
    int base = blockIdx.x * 4096 + threadIdx.x * 4;
    int bs = blocksum[blockIdx.x];
    if (base + 3 < N) {
        int4 o = *(const int4*)&local[base];
        o.x += bs; o.y += bs; o.z += bs; o.w += bs;
        *(int4*)&offsets[base] = o;
        *(int4*)&cursor[base]  = o;
    } else {
        for (int j = 0; j < 4; ++j)
            if (base + j < N) {
                int o = local[base + j] + bs;
                offsets[base + j] = o;
                cursor[base + j]  = o;
            }
    }
}

// ---------------------------------------------------------------------------
// K4: fused edge stream (R5 structure): a_edge dot + exact-slot CSR scatter,
// ONE int4 (16B) per edge via NONTEMPORAL store (bypass L2 reuse-allocation
// for cold scattered lines).
// ---------------------------------------------------------------------------
__global__ __launch_bounds__(256) void k_scatter(
    const float* __restrict__ edge_attr, const int* __restrict__ ei,
    const float* __restrict__ v_edge, int* __restrict__ cursor,
    int4* __restrict__ csr, int E)
{
    __shared__ float vl[HC];
    int t = threadIdx.x;
    if (t < HC) vl[t] = v_edge[t];
    __syncthreads();

    int e = blockIdx.x * 256 + t;
    if (e >= E) return;

    const float4* ea4 = (const float4*)edge_attr + (size_t)e * 8;
    float ae[4] = {0.f, 0.f, 0.f, 0.f};
    #pragma unroll
    for (int j = 0; j < 8; ++j) {
        float4 v = ea4[j];
        #pragma unroll
        for (int h = 0; h < 4; ++h) {
            const float* vh = &vl[h * 32 + j * 4];
            ae[h] += v.x * vh[0] + v.y * vh[1] + v.z * vh[2] + v.w * vh[3];
        }
    }
    int src = ei[e], dst = ei[E + e];
    int pos = atomicAdd(&cursor[dst], 1);
    int4 pk;
    pk.x = src;
    pk.y = (int)pack_bf16(ae[0], ae[1]);
    pk.z = (int)pack_bf16(ae[2], ae[3]);
    pk.w = 0;
    nt_store_i4(&csr[pos], pk);
}

// ---------------------------------------------------------------------------
// K5: fused pull, 16 lanes/node (lane owns 8 channels, uint4 x row read ->
// 1 VMEM instr per edge per 16-lane slice; 4 independent node chains/wave).
// logit finish + softmax denom + weighted sum + bias + LN + LeakyReLU.
// 4-edge groups with 1-ahead prefetch.
// ---------------------------------------------------------------------------
__global__ __launch_bounds__(256) void k_agg(
    const int* __restrict__ offsets, const int4* __restrict__ csr,
    const float* __restrict__ a_src, const float* __restrict__ a_dst,
    const unsigned* __restrict__ xb, const float* __restrict__ bias,
    const float* __restrict__ gamma, const float* __restrict__ beta,
    float* __restrict__ out, int N)
{
    int t = threadIdx.x;
    int node = blockIdx.x * 16 + (t >> 4);
    int lane = t & 15;               // lane owns channels [lane*8, lane*8+8)
    if (node >= N) return;
    int st = offsets[node], en = offsets[node + 1];
    int hsel = lane >> 2;            // 4 lanes per head
    float adst = a_dst[node * 4 + hsel];
    const uint4* x4 = (const uint4*)xb;   // row = 16 uint4 (128 bf16)
    float acc[8] = {0.f, 0.f, 0.f, 0.f, 0.f, 0.f, 0.f, 0.f};
    float denom = 0.f;

    int s_c[4]; float ae_c[4], as_c[4];

    if (st < en) {
        #pragma unroll
        for (int j = 0; j < 4; ++j) {
            bool v = (st + j) < en;
            int a = v ? (st + j) : st;
            int4 pk = csr[a];
            s_c[j] = pk.x;
            unsigned w = (hsel & 2) ? (unsigned)pk.z : (unsigned)pk.y;
            float e = __uint_as_float((hsel & 1) ? (w & 0xffff0000u) : (w << 16));
            ae_c[j] = v ? e : -1e30f;
        }
        #pragma unroll
        for (int j = 0; j < 4; ++j) as_c[j] = a_src[s_c[j] * 4 + hsel];

        for (int p = st; p < en; p += 4) {
            int pn = p + 4;
            int s_n[4]; float ae_n[4], as_n[4];
            #pragma unroll
            for (int j = 0; j < 4; ++j) {
                bool v = (pn + j) < en;
                int a = v ? (pn + j) : st;
                int4 pk = csr[a];
                s_n[j] = pk.x;
                unsigned w = (hsel & 2) ? (unsigned)pk.z : (unsigned)pk.y;
                float e = __uint_as_float((hsel & 1) ? (w & 0xffff0000u) : (w << 16));
                ae_n[j] = v ? e : -1e30f;
            }
            #pragma unroll
            for (int j = 0; j < 4; ++j) as_n[j] = a_src[s_n[j] * 4 + hsel];

            #pragma unroll
            for (int j = 0; j < 4; ++j) {
                float al = as_c[j] + adst + ae_c[j];
                al = (al < 0.f) ? 0.2f * al : al;
                float ex = __expf(al);
                denom += ex;
                uint4 xv = x4[(size_t)s_c[j] * 16 + lane];
                acc[0] += ex * __uint_as_float(xv.x << 16);
                acc[1] += ex * __uint_as_float(xv.x & 0xffff0000u);
                acc[2] += ex * __uint_as_float(xv.y << 16);
                acc[3] += ex * __uint_as_float(xv.y & 0xffff0000u);
                acc[4] += ex * __uint_as_float(xv.z << 16);
                acc[5] += ex * __uint_as_float(xv.z & 0xffff0000u);
                acc[6] += ex * __uint_as_float(xv.w << 16);
                acc[7] += ex * __uint_as_float(xv.w & 0xffff0000u);
            }
            #pragma unroll
            for (int j = 0; j < 4; ++j) {
                s_c[j] = s_n[j]; ae_c[j] = ae_n[j]; as_c[j] = as_n[j];
            }
        }
    }
    float inv = 1.f / (denom + 1e-16f);
    int c = lane * 8;
    float4 b0 = *(const float4*)&bias[c];
    float4 b1 = *(const float4*)&bias[c + 4];
    float o[8];
    o[0] = acc[0] * inv + b0.x; o[1] = acc[1] * inv + b0.y;
    o[2] = acc[2] * inv + b0.z; o[3] = acc[3] * inv + b0.w;
    o[4] = acc[4] * inv + b1.x; o[5] = acc[5] * inv + b1.y;
    o[6] = acc[6] * inv + b1.z; o[7] = acc[7] * inv + b1.w;

    // LayerNorm(128) across 16 lanes x 8 channels
    float s = 0.f;
    #pragma unroll
    for (int i = 0; i < 8; ++i) s += o[i];
    #pragma unroll
    for (int m = 1; m < 16; m <<= 1) s += __shfl_xor(s, m, 16);
    float mu = s * (1.0f / 128.0f);
    float q = 0.f;
    #pragma unroll
    for (int i = 0; i < 8; ++i) { o[i] -= mu; q += o[i] * o[i]; }
    #pragma unroll
    for (int m = 1; m < 16; m <<= 1) q += __shfl_xor(q, m, 16);
    float rstd = rsqrtf(q * (1.0f / 128.0f) + 1e-5f);
    float4 g0 = *(const float4*)&gamma[c];
    float4 g1 = *(const float4*)&gamma[c + 4];
    float4 e0 = *(const float4*)&beta[c];
    float4 e1 = *(const float4*)&beta[c + 4];
    float y[8];
    y[0] = o[0] * rstd * g0.x + e0.x; y[1] = o[1] * rstd * g0.y + e0.y;
    y[2] = o[2] * rstd * g0.z + e0.z; y[3] = o[3] * rstd * g0.w + e0.w;
    y[4] = o[4] * rstd * g1.x + e1.x; y[5] = o[5] * rstd * g1.y + e1.y;
    y[6] = o[6] * rstd * g1.z + e1.z; y[7] = o[7] * rstd * g1.w + e1.w;
    #pragma unroll
    for (int i = 0; i < 8; ++i) y[i] = (y[i] < 0.f) ? 0.01f * y[i] : y[i];
    float4 r0 = {y[0], y[1], y[2], y[3]};
    float4 r1 = {y[4], y[5], y[6], y[7]};
    float4* op = (float4*)out + (size_t)node * 32 + lane * 2;
    nt_store_f4(op, r0);
    nt_store_f4(op + 1, r1);
}

// ---------------------------------------------------------------------------
extern "C" void kernel_launch(void* const* d_in, const int* in_sizes, int n_in,
                              void* d_out, int out_size, void* d_ws, size_t ws_size,
                              hipStream_t stream) {
    const float* point_attr = (const float*)d_in[0];
    const int*   edge_index = (const int*)d_in[1];
    const float* edge_attr  = (const float*)d_in[2];
    const float* W          = (const float*)d_in[3];
    const float* att_src    = (const float*)d_in[4];
    const float* att_dst    = (const float*)d_in[5];
    const float* W_edge     = (const float*)d_in[6];
    const float* att_edge   = (const float*)d_in[7];
    const float* bias       = (const float*)d_in[8];
    const float* ln_gamma   = (const float*)d_in[9];
    const float* ln_beta    = (const float*)d_in[10];

    int N = in_sizes[0] / IN_DIM;
    int E = in_sizes[2] / EDGE_DIM;
    float* out = (float*)d_out;

    char* ws = (char*)d_ws;
    size_t off = 0;
    auto alloc = [&](size_t bytes) {
        void* p = ws + off;
        off += (bytes + 255) & ~(size_t)255;
        return p;
    };
    unsigned* xb     = (unsigned*)alloc((size_t)N * 128 * 2);   // bf16 x
    float* a_src     = (float*)alloc((size_t)N * 4 * 4);
    float* a_dst     = (float*)alloc((size_t)N * 4 * 4);
    int*   degree    = (int*)alloc((size_t)N * 4);
    int*   offsets   = (int*)alloc((size_t)(N + 1) * 4);
    int*   cursor    = (int*)alloc((size_t)N * 4);
    int*   scanloc   = (int*)alloc((size_t)N * 4);
    int*   blocksum  = (int*)alloc(1024 * 4);
    float* v_edge    = (float*)alloc(128 * 4);
    int4*  csr       = (int4*)alloc((size_t)E * 16);

    hipMemsetAsync(degree, 0, (size_t)N * 4, stream);

    int nb = (N + 4095) / 4096;

    k_vedge<<<1, 128, 0, stream>>>(W_edge, att_edge, v_edge);
    k_gemm_x<<<(N + 127) / 128, 256, 0, stream>>>(point_attr, W, att_src, att_dst,
                                                  xb, a_src, a_dst, N);
    k_degree<<<(E + 255) / 256, 256, 0, stream>>>(edge_index, degree, E);
    k_scan_blk<<<nb, 1024, 0, stream>>>(degree, scanloc, blocksum, N);
    k_scan_top<<<1, 1024, 0, stream>>>(blocksum, nb, offsets, N);
    k_scan_add<<<nb, 1024, 0, stream>>>(scanloc, blocksum, offsets, cursor, N);
    k_scatter<<<(E + 255) / 256, 256, 0, stream>>>(edge_attr, edge_index, v_edge,
                                                   cursor, csr, E);
    k_agg<<<(N + 15) / 16, 256, 0, stream>>>(offsets, csr, a_src, a_dst, xb,
                                             bias, ln_gamma, ln_beta, out, N);
}

// Round 10
// 325.213 us; speedup vs baseline: 1.7482x; 1.1952x over previous
//
#include <hip/hip_runtime.h>
#include <hip/hip_bf16.h>

#define IN_DIM 128
#define HC 128   // H*C
#define NH 4     // heads
#define CH 32    // channels per head
#define EDGE_DIM 32

typedef short s8v __attribute__((ext_vector_type(8)));   // 8 bf16 (4 VGPR)
typedef float f4v __attribute__((ext_vector_type(4)));   // mfma acc

// ---------------------------------------------------------------------------
// pack two f32 -> bf16x2 (round-to-nearest-even), result uint
// ---------------------------------------------------------------------------
__device__ __forceinline__ unsigned pack_bf16(float a, float b) {
    unsigned ua = __float_as_uint(a), ub = __float_as_uint(b);
    ua += 0x7fffu + ((ua >> 16) & 1u);
    ub += 0x7fffu + ((ub >> 16) & 1u);
    return (ua >> 16) | (ub & 0xffff0000u);
}
__device__ __forceinline__ unsigned short bf16_1(float a) {
    unsigned ua = __float_as_uint(a);
    ua += 0x7fffu + ((ua >> 16) & 1u);
    return (unsigned short)(ua >> 16);
}

// ---------------------------------------------------------------------------
// K0: v_edge[h][k] = sum_c W_edge[k, h*32+c] * att_edge[h, c]   (4x32 floats)
// ---------------------------------------------------------------------------
__global__ void k_vedge(const float* __restrict__ W_edge,
                        const float* __restrict__ att_edge,
                        float* __restrict__ v_edge) {
    int t = threadIdx.x;           // 128 threads
    int h = t >> 5, k = t & 31;
    float s = 0.f;
    #pragma unroll
    for (int c = 0; c < CH; ++c)
        s += W_edge[k * HC + h * CH + c] * att_edge[h * CH + c];
    v_edge[h * EDGE_DIM + k] = s;
}

// ---------------------------------------------------------------------------
// K0b: Wt[n][k] = bf16(W[k][n])  (128x128, transposed for MFMA B-frag reads)
// ---------------------------------------------------------------------------
__global__ __launch_bounds__(256) void k_prep(
    const float* __restrict__ W, unsigned short* __restrict__ Wt) {
    int id = blockIdx.x * 256 + threadIdx.x;   // 64 blocks
    int n = id >> 7, k = id & 127;
    Wt[n * 128 + k] = bf16_1(W[k * 128 + n]);
}

// ---------------------------------------------------------------------------
// K1: x = point_attr @ W via bf16 MFMA (16x16x32). 64 rows/block, 4 waves.
// A tile bf16 in LDS, slot-XOR swizzle (conflict-free ds_read_b128).
// C written straight to xb (bf16, row-major [node][128]).
// ---------------------------------------------------------------------------
__global__ __launch_bounds__(256) void k_gemm_mfma(
    const float* __restrict__ A, const unsigned short* __restrict__ Wt,
    unsigned short* __restrict__ xb16, int N)
{
    __shared__ unsigned Al[64 * 64];   // [row][k2], 16 KB, slot-swizzled

    int t = threadIdx.x;
    int node0 = blockIdx.x * 64;

    // stage A: 64 rows x 32 float4; convert fp32 -> bf16x2
    const float4* A4 = (const float4*)A;
    #pragma unroll
    for (int it = 0; it < 8; ++it) {
        int id = it * 256 + t;
        int row = id >> 5, c = id & 31;        // c: float4 idx (k = 4c..4c+3)
        float4 v = {0.f, 0.f, 0.f, 0.f};
        if (node0 + row < N) v = A4[(size_t)(node0 + row) * 32 + c];
        unsigned u0 = pack_bf16(v.x, v.y);
        unsigned u1 = pack_bf16(v.z, v.w);
        int k2 = 2 * c;                        // uint index in row (0..63)
        int slot = k2 >> 2;                    // 16B slot (0..15)
        int idx = ((slot ^ (row & 15)) << 2) | (k2 & 3);
        Al[row * 64 + idx]     = u0;
        Al[row * 64 + idx + 1] = u1;
    }
    __syncthreads();

    int l = t & 63;
    int w = t >> 6;                 // wave id: rows w*16..w*16+15
    int lrow = l & 15;
    int lk   = l >> 4;              // 0..3

    // A fragments: row = w*16+lrow, k = kb*32 + lk*8 + j
    s8v afr[4];
    #pragma unroll
    for (int kb = 0; kb < 4; ++kb) {
        int slot = kb * 4 + lk;     // k2 = kb*16 + lk*4 -> slot
        const unsigned* p = &Al[(w * 16 + lrow) * 64 + ((slot ^ lrow) << 2)];
        afr[kb] = *(const s8v*)p;
    }

    // loop over 8 col-tiles; B frag: Wt[col][k] contiguous in k
    #pragma unroll
    for (int ct = 0; ct < 8; ++ct) {
        int col = ct * 16 + lrow;
        f4v acc = {0.f, 0.f, 0.f, 0.f};
        #pragma unroll
        for (int kb = 0; kb < 4; ++kb) {
            s8v bfr = *(const s8v*)&Wt[col * 128 + kb * 32 + lk * 8];
            acc = __builtin_amdgcn_mfma_f32_16x16x32_bf16(afr[kb], bfr, acc, 0, 0, 0);
        }
        #pragma unroll
        for (int r = 0; r < 4; ++r) {
            int node = node0 + w * 16 + lk * 4 + r;
            if (node < N) xb16[(size_t)node * 128 + col] = bf16_1(acc[r]);
        }
    }
}

// ---------------------------------------------------------------------------
// K1b: a_src/a_dst from bf16 x. 16 lanes/node, lane owns 8 channels
// (head = lane>>2); 4-lane shfl reduce per head.
// ---------------------------------------------------------------------------
__global__ __launch_bounds__(256) void k_att(
    const unsigned* __restrict__ xb, const float* __restrict__ att_src,
    const float* __restrict__ att_dst, float* __restrict__ a_src,
    float* __restrict__ a_dst, int N)
{
    int t = threadIdx.x;
    int node = blockIdx.x * 16 + (t >> 4);
    int lane = t & 15;
    if (node >= N) return;
    const uint4* x4 = (const uint4*)xb;
    uint4 xv = x4[(size_t)node * 16 + lane];
    int c = lane * 8;
    float xs[8];
    xs[0] = __uint_as_float(xv.x << 16); xs[1] = __uint_as_float(xv.x & 0xffff0000u);
    xs[2] = __uint_as_float(xv.y << 16); xs[3] = __uint_as_float(xv.y & 0xffff0000u);
    xs[4] = __uint_as_float(xv.z << 16); xs[5] = __uint_as_float(xv.z & 0xffff0000u);
    xs[6] = __uint_as_float(xv.w << 16); xs[7] = __uint_as_float(xv.w & 0xffff0000u);
    float ps = 0.f, pd = 0.f;
    #pragma unroll
    for (int i = 0; i < 8; ++i) {
        ps += xs[i] * att_src[c + i];
        pd += xs[i] * att_dst[c + i];
    }
    ps += __shfl_xor(ps, 1); ps += __shfl_xor(ps, 2);
    pd += __shfl_xor(pd, 1); pd += __shfl_xor(pd, 2);
    if ((lane & 3) == 0) {
        a_src[node * 4 + (lane >> 2)] = ps;
        a_dst[node * 4 + (lane >> 2)] = pd;
    }
}

// ---------------------------------------------------------------------------
// K2: degree histogram (int atomics only, dst stream)
// ---------------------------------------------------------------------------
__global__ __launch_bounds__(256) void k_degree(const int* __restrict__ ei,
                                                int* __restrict__ degree, int E) {
    int e = blockIdx.x * 256 + threadIdx.x;
    if (e < E) atomicAdd(&degree[ei[E + e]], 1);
}

// ---------------------------------------------------------------------------
// K3a: per-block scan. 1024 thr x 4 elem (int4).
// ---------------------------------------------------------------------------
__global__ __launch_bounds__(1024) void k_scan_blk(
    const int* __restrict__ degree, int* __restrict__ local,
    int* __restrict__ blocksum, int N)
{
    __shared__ int sums[1024];
    int t = threadIdx.x;
    int base = blockIdx.x * 4096 + t * 4;
    int4 d = {0, 0, 0, 0};
    if (base + 3 < N) d = *(const int4*)&degree[base];
    else {
        if (base + 0 < N) d.x = degree[base + 0];
        if (base + 1 < N) d.y = degree[base + 1];
        if (base + 2 < N) d.z = degree[base + 2];
        if (base + 3 < N) d.w = degree[base + 3];
    }
    int s = d.x + d.y + d.z + d.w;
    sums[t] = s;
    __syncthreads();
    #pragma unroll
    for (int dd = 1; dd < 1024; dd <<= 1) {
        int v = (t >= dd) ? sums[t - dd] : 0;
        __syncthreads();
        sums[t] += v;
        __syncthreads();
    }
    int ex = sums[t] - s;
    if (t == 1023) blocksum[blockIdx.x] = sums[1023];
    int4 o;
    o.x = ex;
    o.y = o.x + d.x;
    o.z = o.y + d.y;
    o.w = o.z + d.z;
    if (base + 3 < N) *(int4*)&local[base] = o;
    else {
        if (base + 0 < N) local[base + 0] = o.x;
        if (base + 1 < N) local[base + 1] = o.y;
        if (base + 2 < N) local[base + 2] = o.z;
        if (base + 3 < N) local[base + 3] = o.w;
    }
}

// ---------------------------------------------------------------------------
// K3b: scan block sums in-place -> exclusive block bases; offsets[N] = E.
// ---------------------------------------------------------------------------
__global__ __launch_bounds__(1024) void k_scan_top(
    int* __restrict__ blocksum, int nb, int* __restrict__ offsets, int N)
{
    __shared__ int sums[1024];
    int t = threadIdx.x;
    int v = (t < nb) ? blocksum[t] : 0;
    sums[t] = v;
    __syncthreads();
    #pragma unroll
    for (int d = 1; d < 1024; d <<= 1) {
        int u = (t >= d) ? sums[t - d] : 0;
        __syncthreads();
        sums[t] += u;
        __syncthreads();
    }
    if (t < nb) blocksum[t] = sums[t] - v;
    if (t == nb - 1) offsets[N] = sums[t];
}

// ---------------------------------------------------------------------------
// K3c: add block base; write offsets + cursor.
// ---------------------------------------------------------------------------
__global__ __launch_bounds__(1024) void k_scan_add(
    const int* __restrict__ local, const int* __restrict__ blocksum,
    int* __restrict__ offsets, int* __restrict__ cursor, int N)
{
    int base = blockIdx.x * 4096 + threadIdx.x * 4;
    int bs = blocksum[blockIdx.x];
    if (base + 3 < N) {
        int4 o = *(const int4*)&local[base];
        o.x += bs; o.y += bs; o.z += bs; o.w += bs;
        *(int4*)&offsets[base] = o;
        *(int4*)&cursor[base]  = o;
    } else {
        for (int j = 0; j < 4; ++j)
            if (base + j < N) {
                int o = local[base + j] + bs;
                offsets[base + j] = o;
                cursor[base + j]  = o;
            }
    }
}

// ---------------------------------------------------------------------------
// K4: fused edge stream (R5 winner): a_edge dot + exact-slot CSR scatter,
// ONE int4 (16B) per edge, plain store (NT regressed in R9).
// ---------------------------------------------------------------------------
__global__ __launch_bounds__(256) void k_scatter(
    const float* __restrict__ edge_attr, const int* __restrict__ ei,
    const float* __restrict__ v_edge, int* __restrict__ cursor,
    int4* __restrict__ csr, int E)
{
    __shared__ float vl[HC];
    int t = threadIdx.x;
    if (t < HC) vl[t] = v_edge[t];
    __syncthreads();

    int e = blockIdx.x * 256 + t;
    if (e >= E) return;

    const float4* ea4 = (const float4*)edge_attr + (size_t)e * 8;
    float ae[4] = {0.f, 0.f, 0.f, 0.f};
    #pragma unroll
    for (int j = 0; j < 8; ++j) {
        float4 v = ea4[j];
        #pragma unroll
        for (int h = 0; h < 4; ++h) {
            const float* vh = &vl[h * 32 + j * 4];
            ae[h] += v.x * vh[0] + v.y * vh[1] + v.z * vh[2] + v.w * vh[3];
        }
    }
    int src = ei[e], dst = ei[E + e];
    int pos = atomicAdd(&cursor[dst], 1);
    int4 pk;
    pk.x = src;
    pk.y = (int)pack_bf16(ae[0], ae[1]);
    pk.z = (int)pack_bf16(ae[2], ae[3]);
    pk.w = 0;
    csr[pos] = pk;
}

// ---------------------------------------------------------------------------
// K5: fused pull, 16 lanes/node (lane owns 8 channels, uint4 x row read).
// logit finish + softmax denom + weighted sum + bias + LN + LeakyReLU.
// 4-edge groups with 1-ahead prefetch.
// ---------------------------------------------------------------------------
__global__ __launch_bounds__(256) void k_agg(
    const int* __restrict__ offsets, const int4* __restrict__ csr,
    const float* __restrict__ a_src, const float* __restrict__ a_dst,
    const unsigned* __restrict__ xb, const float* __restrict__ bias,
    const float* __restrict__ gamma, const float* __restrict__ beta,
    float* __restrict__ out, int N)
{
    int t = threadIdx.x;
    int node = blockIdx.x * 16 + (t >> 4);
    int lane = t & 15;               // lane owns channels [lane*8, lane*8+8)
    if (node >= N) return;
    int st = offsets[node], en = offsets[node + 1];
    int hsel = lane >> 2;            // 4 lanes per head
    float adst = a_dst[node * 4 + hsel];
    const uint4* x4 = (const uint4*)xb;   // row = 16 uint4 (128 bf16)
    float acc[8] = {0.f, 0.f, 0.f, 0.f, 0.f, 0.f, 0.f, 0.f};
    float denom = 0.f;

    int s_c[4]; float ae_c[4], as_c[4];

    if (st < en) {
        #pragma unroll
        for (int j = 0; j < 4; ++j) {
            bool v = (st + j) < en;
            int a = v ? (st + j) : st;
            int4 pk = csr[a];
            s_c[j] = pk.x;
            unsigned w = (hsel & 2) ? (unsigned)pk.z : (unsigned)pk.y;
            float e = __uint_as_float((hsel & 1) ? (w & 0xffff0000u) : (w << 16));
            ae_c[j] = v ? e : -1e30f;
        }
        #pragma unroll
        for (int j = 0; j < 4; ++j) as_c[j] = a_src[s_c[j] * 4 + hsel];

        for (int p = st; p < en; p += 4) {
            int pn = p + 4;
            int s_n[4]; float ae_n[4], as_n[4];
            #pragma unroll
            for (int j = 0; j < 4; ++j) {
                bool v = (pn + j) < en;
                int a = v ? (pn + j) : st;
                int4 pk = csr[a];
                s_n[j] = pk.x;
                unsigned w = (hsel & 2) ? (unsigned)pk.z : (unsigned)pk.y;
                float e = __uint_as_float((hsel & 1) ? (w & 0xffff0000u) : (w << 16));
                ae_n[j] = v ? e : -1e30f;
            }
            #pragma unroll
            for (int j = 0; j < 4; ++j) as_n[j] = a_src[s_n[j] * 4 + hsel];

            #pragma unroll
            for (int j = 0; j < 4; ++j) {
                float al = as_c[j] + adst + ae_c[j];
                al = (al < 0.f) ? 0.2f * al : al;
                float ex = __expf(al);
                denom += ex;
                uint4 xv = x4[(size_t)s_c[j] * 16 + lane];
                acc[0] += ex * __uint_as_float(xv.x << 16);
                acc[1] += ex * __uint_as_float(xv.x & 0xffff0000u);
                acc[2] += ex * __uint_as_float(xv.y << 16);
                acc[3] += ex * __uint_as_float(xv.y & 0xffff0000u);
                acc[4] += ex * __uint_as_float(xv.z << 16);
                acc[5] += ex * __uint_as_float(xv.z & 0xffff0000u);
                acc[6] += ex * __uint_as_float(xv.w << 16);
                acc[7] += ex * __uint_as_float(xv.w & 0xffff0000u);
            }
            #pragma unroll
            for (int j = 0; j < 4; ++j) {
                s_c[j] = s_n[j]; ae_c[j] = ae_n[j]; as_c[j] = as_n[j];
            }
        }
    }
    float inv = 1.f / (denom + 1e-16f);
    int c = lane * 8;
    float4 b0 = *(const float4*)&bias[c];
    float4 b1 = *(const float4*)&bias[c + 4];
    float o[8];
    o[0] = acc[0] * inv + b0.x; o[1] = acc[1] * inv + b0.y;
    o[2] = acc[2] * inv + b0.z; o[3] = acc[3] * inv + b0.w;
    o[4] = acc[4] * inv + b1.x; o[5] = acc[5] * inv + b1.y;
    o[6] = acc[6] * inv + b1.z; o[7] = acc[7] * inv + b1.w;

    // LayerNorm(128) across 16 lanes x 8 channels
    float s = 0.f;
    #pragma unroll
    for (int i = 0; i < 8; ++i) s += o[i];
    #pragma unroll
    for (int m = 1; m < 16; m <<= 1) s += __shfl_xor(s, m, 16);
    float mu = s * (1.0f / 128.0f);
    float q = 0.f;
    #pragma unroll
    for (int i = 0; i < 8; ++i) { o[i] -= mu; q += o[i] * o[i]; }
    #pragma unroll
    for (int m = 1; m < 16; m <<= 1) q += __shfl_xor(q, m, 16);
    float rstd = rsqrtf(q * (1.0f / 128.0f) + 1e-5f);
    float4 g0 = *(const float4*)&gamma[c];
    float4 g1 = *(const float4*)&gamma[c + 4];
    float4 e0 = *(const float4*)&beta[c];
    float4 e1 = *(const float4*)&beta[c + 4];
    float y[8];
    y[0] = o[0] * rstd * g0.x + e0.x; y[1] = o[1] * rstd * g0.y + e0.y;
    y[2] = o[2] * rstd * g0.z + e0.z; y[3] = o[3] * rstd * g0.w + e0.w;
    y[4] = o[4] * rstd * g1.x + e1.x; y[5] = o[5] * rstd * g1.y + e1.y;
    y[6] = o[6] * rstd * g1.z + e1.z; y[7] = o[7] * rstd * g1.w + e1.w;
    #pragma unroll
    for (int i = 0; i < 8; ++i) y[i] = (y[i] < 0.f) ? 0.01f * y[i] : y[i];
    float4 r0 = {y[0], y[1], y[2], y[3]};
    float4 r1 = {y[4], y[5], y[6], y[7]};
    float4* op = (float4*)out + (size_t)node * 32 + lane * 2;
    op[0] = r0;
    op[1] = r1;
}

// ---------------------------------------------------------------------------
extern "C" void kernel_launch(void* const* d_in, const int* in_sizes, int n_in,
                              void* d_out, int out_size, void* d_ws, size_t ws_size,
                              hipStream_t stream) {
    const float* point_attr = (const float*)d_in[0];
    const int*   edge_index = (const int*)d_in[1];
    const float* edge_attr  = (const float*)d_in[2];
    const float* W          = (const float*)d_in[3];
    const float* att_src    = (const float*)d_in[4];
    const float* att_dst    = (const float*)d_in[5];
    const float* W_edge     = (const float*)d_in[6];
    const float* att_edge   = (const float*)d_in[7];
    const float* bias       = (const float*)d_in[8];
    const float* ln_gamma   = (const float*)d_in[9];
    const float* ln_beta    = (const float*)d_in[10];

    int N = in_sizes[0] / IN_DIM;
    int E = in_sizes[2] / EDGE_DIM;
    float* out = (float*)d_out;

    char* ws = (char*)d_ws;
    size_t off = 0;
    auto alloc = [&](size_t bytes) {
        void* p = ws + off;
        off += (bytes + 255) & ~(size_t)255;
        return p;
    };
    unsigned* xb     = (unsigned*)alloc((size_t)N * 128 * 2);   // bf16 x
    float* a_src     = (float*)alloc((size_t)N * 4 * 4);
    float* a_dst     = (float*)alloc((size_t)N * 4 * 4);
    int*   degree    = (int*)alloc((size_t)N * 4);
    int*   offsets   = (int*)alloc((size_t)(N + 1) * 4);
    int*   cursor    = (int*)alloc((size_t)N * 4);
    int*   scanloc   = (int*)alloc((size_t)N * 4);
    int*   blocksum  = (int*)alloc(1024 * 4);
    float* v_edge    = (float*)alloc(128 * 4);
    unsigned short* Wt = (unsigned short*)alloc(128 * 128 * 2);
    int4*  csr       = (int4*)alloc((size_t)E * 16);

    hipMemsetAsync(degree, 0, (size_t)N * 4, stream);

    int nb = (N + 4095) / 4096;

    k_vedge<<<1, 128, 0, stream>>>(W_edge, att_edge, v_edge);
    k_prep<<<64, 256, 0, stream>>>(W, Wt);
    k_gemm_mfma<<<(N + 63) / 64, 256, 0, stream>>>(point_attr, Wt,
                                                   (unsigned short*)xb, N);
    k_att<<<(N + 15) / 16, 256, 0, stream>>>(xb, att_src, att_dst,
                                             a_src, a_dst, N);
    k_degree<<<(E + 255) / 256, 256, 0, stream>>>(edge_index, degree, E);
    k_scan_blk<<<nb, 1024, 0, stream>>>(degree, scanloc, blocksum, N);
    k_scan_top<<<1, 1024, 0, stream>>>(blocksum, nb, offsets, N);
    k_scan_add<<<nb, 1024, 0, stream>>>(scanloc, blocksum, offsets, cursor, N);
    k_scatter<<<(E + 255) / 256, 256, 0, stream>>>(edge_attr, edge_index, v_edge,
                                                   cursor, csr, E);
    k_agg<<<(N + 15) / 16, 256, 0, stream>>>(offsets, csr, a_src, a_dst, xb,
                                             bias, ln_gamma, ln_beta, out, N);
}